// Round 2
// baseline (519.588 us; speedup 1.0000x reference)
//
#include <hip/hip_runtime.h>

// x: (T=128, B=4, E=10000, F=16) fp32, dummy_index d = 0.
// out: (128, 4, 10000, 15) fp32 = tanh(cumsum_T(x[...,1:] * dt)),
// dt[0] = t0+t1, dt[k] = t[k]-t[k-1], t = x[...,0].
//
// Round-2 mapping: 8 threads per (b,e) group (was 4) -> 320,000 threads,
// 1250 blocks, 4.88 waves/SIMD (2x occupancy for latency hiding).
// Each thread loads one float2 (features 2*sub, 2*sub+1) per timestep
// (8 B/lane, coalesced). dt channel = group leader's .x, broadcast via
// ds_swizzle BitMode and=0x18 (src = lane & ~7 within each 32-half).
//
// Stores: per-wave LDS repack (8 groups x 15 = 120 floats = 480 B strip),
// lanes 0..29 write contiguous float4 -> 7.5 lines/wave-store instead of
// ~120 scattered line-transactions.
//
// Sync: DS ops are in-order within a wave, so the ds_read cannot bypass
// the ds_writes in hardware; only compiler reordering must be prevented.
// wave_barrier is a zero-instruction code-motion fence (replaces last
// round's full lgkmcnt(0) drain + "memory" clobber, which serialized the
// DS pipe and pinned the scheduler every timestep).
//
// Prefetch: 3-deep rotation (v, n1, n2, n3) keeps ~3 global loads in
// flight per wave; with 2x waves that's ~6x the previous in-flight bytes.

#define TT    128
#define X2_T  320000           // per-t stride in float2 units (B*E*F/2)
#define O_T4  150000           // per-t stride in float4 units for out (B*E*15/4)

__device__ __forceinline__ float fast_tanh(float x) {
  // tanh(x) = 1 - 2/(exp(2x)+1); saturates correctly at +/-inf.
  float e = __expf(2.0f * x);
  return 1.0f - __fdividef(2.0f, e + 1.0f);
}

// Broadcast lane (8k).x to lanes 8k..8k+7.
// ds_swizzle BitMode offset = (xor<<10)|(or<<5)|and with and=0x18:
// src_lane = lane & 0x18 = lane & ~7 (within each 32-lane half; 8-lane
// groups never straddle the half boundary).
__device__ __forceinline__ float oct_bcast0(float v) {
  return __int_as_float(__builtin_amdgcn_ds_swizzle(__float_as_int(v), 0x18));
}

__global__ __launch_bounds__(256) void integ_kernel(const float* __restrict__ x,
                                                    float* __restrict__ out) {
  // Per-wave staging strip: 8 groups * 15 floats = 120 floats = 480 B.
  __shared__ __align__(16) float stage[4][120];

  const int tid  = threadIdx.x;
  const int gid  = blockIdx.x * 256 + tid;   // grid exact: 1250*256 = 320000
  const int idx  = gid >> 3;                 // (b,e) group index, 0..39999
  const int sub  = gid & 7;                  // which float2 within F=16
  const int wid  = tid >> 6;                 // wave in block, 0..3
  const int lane = tid & 63;
  const int g    = lane >> 3;                // group within wave, 0..7

  const float2* xv = reinterpret_cast<const float2*>(x) + ((size_t)idx * 8 + sub);

  // LDS write slot: input features f = 2*sub, 2*sub+1 -> output jo = f-1.
  // sub==0: jo=-1 is the dt channel (skipped), jo=0 is sw[0].
  float* sw = &stage[wid][0] + (g * 15 + 2 * sub);
  // Coalesced store: lanes 0..29 each own one float4 of the 120-float strip.
  const float4* ls = reinterpret_cast<const float4*>(&stage[wid][0]) + lane;
  const int gbase = blockIdx.x * 32 + wid * 8;   // first group of this wave
  float4* op = reinterpret_cast<float4*>(out + (size_t)gbase * 15) + lane;

  // --- prologue: load t = 0..3 (3-deep prefetch) ---
  float2 v0 = xv[0];
  float2 v1 = xv[(size_t)X2_T];
  float2 v2 = xv[(size_t)2 * X2_T];
  float2 v3 = xv[(size_t)3 * X2_T];

  // --- t = 0: dt = t[0] + t[1] ---
  float t0 = oct_bcast0(v0.x);
  float t1 = oct_bcast0(v1.x);
  float dt = t0 + t1;
  float a0 = v0.x * dt;
  float a1 = v0.y * dt;

  if (sub) sw[-1] = fast_tanh(a0);
  sw[0] = fast_tanh(a1);
  __builtin_amdgcn_wave_barrier();      // writes before read (compiler fence;
                                        // HW DS pipe is in-order per wave)
  if (lane < 30) op[0] = *ls;
  __builtin_amdgcn_wave_barrier();      // read before next iteration's writes

  float tprev = t0;
  float2 cur = v1, n1 = v2, n2 = v3;

  // --- t = 1..127: dt = t[k] - t[k-1] ---
#pragma unroll 4
  for (int t = 1; t < TT; ++t) {
    // Prefetch t+3 (clamped; tail reloads are same-address, L2-hot).
    int tn = (t + 3 < TT) ? t + 3 : TT - 1;
    float2 n3 = xv[(size_t)tn * X2_T];

    float tc = oct_bcast0(cur.x);
    dt = tc - tprev;
    a0 = fmaf(cur.x, dt, a0);
    a1 = fmaf(cur.y, dt, a1);

    if (sub) sw[-1] = fast_tanh(a0);
    sw[0] = fast_tanh(a1);
    __builtin_amdgcn_wave_barrier();
    if (lane < 30) op[(size_t)t * O_T4] = *ls;
    __builtin_amdgcn_wave_barrier();

    tprev = tc;
    cur = n1; n1 = n2; n2 = n3;
  }
}

extern "C" void kernel_launch(void* const* d_in, const int* in_sizes, int n_in,
                              void* d_out, int out_size, void* d_ws, size_t ws_size,
                              hipStream_t stream) {
  const float* x = (const float*)d_in[0];
  float* out = (float*)d_out;
  // 40000 groups * 8 threads = 320000 threads = 1250 blocks of 256 exactly.
  integ_kernel<<<dim3(1250), dim3(256), 0, stream>>>(x, out);
}